// Round 7
// baseline (523.775 us; speedup 1.0000x reference)
//
#include <hip/hip_runtime.h>
#include <stdint.h>

// VQVAE quantise, fp32 in/out.
// K0 convert_dict: dict f32 -> f16 hi/lo + d_sq, written ONCE into the one-hot
//     output region (used as scratch; overwritten by K2 afterwards).
// K1 argmin_mfma2: barrier-free K-loop, B-frags direct from global f16 hi/lo,
//     runtime layout probes for C/D attribution (proven in round 6).
// K2 onehot_nt: fused zero-fill + scatter with nontemporal stores.
// ws: idx int32 [256*64] only.

#define B_SZ 256
#define C_SZ 64
#define E_SZ 128
#define S_SZ 4096
#define CW   8192

typedef __attribute__((ext_vector_type(4))) float    float4a;
typedef __attribute__((ext_vector_type(8))) _Float16 half8;

__device__ __forceinline__ void split8(float4a f0, float4a f1, half8& hi, half8& lo) {
    #pragma unroll
    for (int j = 0; j < 4; ++j) {
        _Float16 h0 = (_Float16)f0[j];
        hi[j]     = h0;
        lo[j]     = (_Float16)(f0[j] - (float)h0);
        _Float16 h1 = (_Float16)f1[j];
        hi[4 + j] = h1;
        lo[4 + j] = (_Float16)(f1[j] - (float)h1);
    }
}

// ---------------- K0: dict f32 -> (dh, dl) f16 + dsq f32 ----------------
// grid 16384 x 256: block handles 16 dict rows (2048 elems, 8 per thread).
__global__ __launch_bounds__(256) void convert_dict(
    const float* __restrict__ dict,
    _Float16* __restrict__ dh, _Float16* __restrict__ dl,
    float* __restrict__ dsq)
{
    __shared__ float part[256];
    const int tid = threadIdx.x;
    const int r   = tid >> 4;          // local row 0..15
    const int ck  = tid & 15;          // 8-elem chunk 0..15
    const size_t base = (size_t)blockIdx.x * 2048;
    const size_t off  = base + (size_t)r * E_SZ + ck * 8;

    float4a f0 = *reinterpret_cast<const float4a*>(dict + off);
    float4a f1 = *reinterpret_cast<const float4a*>(dict + off + 4);
    half8 h, l;
    split8(f0, f1, h, l);
    *reinterpret_cast<half8*>(dh + off) = h;
    *reinterpret_cast<half8*>(dl + off) = l;

    float p = 0.f;
    #pragma unroll
    for (int j = 0; j < 4; ++j) { p = fmaf(f0[j], f0[j], p); p = fmaf(f1[j], f1[j], p); }
    part[tid] = p;
    __syncthreads();
    if (ck == 0) {
        float a = 0.f;
        #pragma unroll
        for (int j = 0; j < 16; ++j) a += part[r * 16 + j];
        dsq[blockIdx.x * 16 + r] = a;
    }
}

// ---------------- K1: barrier-free MFMA argmin + cw gather ----------------
// grid 512 = (btile 0..7) x (c 0..63), block 256 = 4 waves (nquad 0..3).
// Block: 32 b-rows x all 4096 codes of one c.
__global__ __launch_bounds__(256) void argmin_mfma2(
    const float* __restrict__ x,
    const _Float16* __restrict__ dh,
    const _Float16* __restrict__ dl,
    const float* __restrict__ dsq_g,
    const float* __restrict__ dict,
    int* __restrict__ idx_out,
    float* __restrict__ cw_out)
{
    __shared__ float s_dsq[S_SZ];     // 16 KB
    __shared__ float rv[32 * 64];     // 8 KB
    __shared__ int   ri[32 * 64];     // 8 KB
    __shared__ int   fid[32];

    const int tid   = threadIdx.x;
    const int lane  = tid & 63;
    const int quad  = lane >> 4;
    const int l15   = lane & 15;
    const int nquad = tid >> 6;       // wave id 0..3
    const int c     = blockIdx.x & 63;
    const int btile = blockIdx.x >> 6; // 0..7

    // runtime layout probes (proven round 6)
    int m_attr[4], n_attr[4];
    {
        half8 ones, enc;
        #pragma unroll
        for (int j = 0; j < 8; ++j) { ones[j] = (_Float16)1.0f; enc[j] = (_Float16)(float)l15; }
        float4a z = {0.f, 0.f, 0.f, 0.f};
        float4a pr = __builtin_amdgcn_mfma_f32_16x16x32_f16(enc, ones, z, 0, 0, 0);
        float4a pc = __builtin_amdgcn_mfma_f32_16x16x32_f16(ones, enc, z, 0, 0, 0);
        #pragma unroll
        for (int r = 0; r < 4; ++r) {
            m_attr[r] = (int)(pr[r] * 0.03125f + 0.5f);
            n_attr[r] = (int)(pc[r] * 0.03125f + 0.5f);
        }
    }

    // stage d_sq c-slice into LDS (only barrier-dependent phase)
    {
        const float4a* src = reinterpret_cast<const float4a*>(dsq_g + c * S_SZ);
        float4a* dst = reinterpret_cast<float4a*>(s_dsq);
        #pragma unroll
        for (int i = 0; i < 4; ++i) dst[tid + i * 256] = src[tid + i * 256];
    }

    // A fragments in regs for whole kernel: believed A[m=l15][k=kk*32+quad*8+j]
    half8 ah[2][4], al[2][4];
    #pragma unroll
    for (int mi = 0; mi < 2; ++mi) {
        int b = btile * 32 + mi * 16 + l15;
        const float* xr = x + (size_t)b * CW + c * E_SZ;
        #pragma unroll
        for (int kk = 0; kk < 4; ++kk) {
            float4a f0 = *reinterpret_cast<const float4a*>(xr + kk * 32 + quad * 8);
            float4a f1 = *reinterpret_cast<const float4a*>(xr + kk * 32 + quad * 8 + 4);
            split8(f0, f1, ah[mi][kk], al[mi][kk]);
        }
    }
    __syncthreads();

    float bestv[8];
    int   besti[8];
    #pragma unroll
    for (int i = 0; i < 8; ++i) { bestv[i] = 3.4e38f; besti[i] = 0; }

    for (int s0 = 0; s0 < S_SZ; s0 += 128) {
        // B-frags straight from global f16: believed B[n=l15][k=kk*32+quad*8+j]
        half8 bhf[2][4], blf[2][4];
        #pragma unroll
        for (int ni = 0; ni < 2; ++ni) {
            int sl = nquad * 32 + ni * 16 + l15;
            size_t row = ((size_t)c * S_SZ + s0 + sl) * E_SZ;
            #pragma unroll
            for (int kk = 0; kk < 4; ++kk) {
                bhf[ni][kk] = *reinterpret_cast<const half8*>(dh + row + kk * 32 + quad * 8);
                blf[ni][kk] = *reinterpret_cast<const half8*>(dl + row + kk * 32 + quad * 8);
            }
        }

        float4a acc[2][2] = {{{0.f,0.f,0.f,0.f},{0.f,0.f,0.f,0.f}},
                             {{0.f,0.f,0.f,0.f},{0.f,0.f,0.f,0.f}}};
        #pragma unroll
        for (int kk = 0; kk < 4; ++kk)
            #pragma unroll
            for (int mi = 0; mi < 2; ++mi)
                #pragma unroll
                for (int ni = 0; ni < 2; ++ni) {
                    acc[mi][ni] = __builtin_amdgcn_mfma_f32_16x16x32_f16(
                        ah[mi][kk], bhf[ni][kk], acc[mi][ni], 0, 0, 0);
                    acc[mi][ni] = __builtin_amdgcn_mfma_f32_16x16x32_f16(
                        ah[mi][kk], blf[ni][kk], acc[mi][ni], 0, 0, 0);
                    acc[mi][ni] = __builtin_amdgcn_mfma_f32_16x16x32_f16(
                        al[mi][kk], bhf[ni][kk], acc[mi][ni], 0, 0, 0);
                }

        // dist = d_sq - 2*cross (x_sq argmin-invariant, dropped — proven round 6)
        #pragma unroll
        for (int ni = 0; ni < 2; ++ni)
            #pragma unroll
            for (int r = 0; r < 4; ++r) {
                int sl = nquad * 32 + ni * 16 + n_attr[r];
                float dsq = s_dsq[s0 + sl];
                int sg = s0 + sl;
                #pragma unroll
                for (int mi = 0; mi < 2; ++mi) {
                    float dist = dsq - 2.0f * acc[mi][ni][r];
                    int slot = mi * 4 + r;
                    if (dist < bestv[slot]) { bestv[slot] = dist; besti[slot] = sg; }
                }
            }
    }

    // bijective 32x64 dump with true attribution
    #pragma unroll
    for (int mi = 0; mi < 2; ++mi)
        #pragma unroll
        for (int r = 0; r < 4; ++r) {
            int row = mi * 16 + m_attr[r];
            int col = nquad * 16 + n_attr[r];
            rv[row * 64 + col] = bestv[mi * 4 + r];
            ri[row * 64 + col] = besti[mi * 4 + r];
        }
    __syncthreads();

    if (tid < 32) {
        float bv = 3.4e38f; int bi = 0x7fffffff;
        for (int j = 0; j < 64; ++j) {
            float v = rv[tid * 64 + j];
            int   i = ri[tid * 64 + j];
            if (v < bv || (v == bv && i < bi)) { bv = v; bi = i; }  // first-occurrence
        }
        idx_out[(btile * 32 + tid) * C_SZ + c] = bi;
        fid[tid] = bi;
    }
    __syncthreads();

    // gather cw_embed from original f32 dict: 32 rows x 32 float4 chunks
    #pragma unroll
    for (int u = tid; u < 32 * 32; u += 256) {
        int row = u >> 5, ch = u & 31;
        int bi = fid[row];
        float4a v = *reinterpret_cast<const float4a*>(
            dict + ((size_t)c * S_SZ + bi) * E_SZ + ch * 4);
        *reinterpret_cast<float4a*>(
            cw_out + (size_t)(btile * 32 + row) * CW + c * E_SZ + ch * 4) = v;
    }
}

// ---------------- K2: fused zero-fill + ones, nontemporal ----------------
// 16.78M float4 chunks; 4.19M threads x 4 chunks (stride = thread count).
__global__ __launch_bounds__(256) void onehot_nt(const int* __restrict__ idx,
                                                 float* __restrict__ oh) {
    const unsigned t = blockIdx.x * 256 + threadIdx.x;    // 0..4194303
    #pragma unroll
    for (int i = 0; i < 4; ++i) {
        unsigned q = t + (unsigned)i * 4194304u;          // float4 chunk id
        unsigned row = q >> 10;                           // (b*64+c)
        int target = idx[row];
        unsigned sbase = (q & 1023u) * 4u;
        float4a v = {0.f, 0.f, 0.f, 0.f};
        unsigned d = (unsigned)(target - (int)sbase);
        if (d < 4u) v[d] = 1.0f;
        __builtin_nontemporal_store(v, reinterpret_cast<float4a*>(oh) + q);
    }
}

extern "C" void kernel_launch(void* const* d_in, const int* in_sizes, int n_in,
                              void* d_out, int out_size, void* d_ws, size_t ws_size,
                              hipStream_t stream) {
    const float* x    = (const float*)d_in[0];
    const float* dict = (const float*)d_in[1];
    float* out = (float*)d_out;
    int* idx = (int*)d_ws;
    float* oh = out + (size_t)B_SZ * CW;

    // scratch inside the one-hot region (268 MB; overwritten by K2 afterwards)
    char* scr = (char*)oh;
    _Float16* dh  = (_Float16*)scr;                      // 67.1 MB
    _Float16* dl  = (_Float16*)(scr + 67108864);         // 67.1 MB
    float*    dsq = (float*)   (scr + 134217728);        // 1.05 MB

    convert_dict<<<dim3(16384), dim3(256), 0, stream>>>(dict, dh, dl, dsq);
    argmin_mfma2<<<dim3(512), dim3(256), 0, stream>>>(x, dh, dl, dsq, dict, idx, out);
    onehot_nt<<<dim3(16384), dim3(256), 0, stream>>>(idx, oh);
}